// Round 6
// baseline (143.828 us; speedup 1.0000x reference)
//
#include <hip/hip_runtime.h>
#include <hip/hip_bf16.h>
#include <stdint.h>
#include <stddef.h>

#define B_  4
#define S_  2048
#define D_  1024
#define TB_ 128

typedef float v4f  __attribute__((ext_vector_type(4)));
typedef short s16x4 __attribute__((ext_vector_type(4)));
typedef short s16x8 __attribute__((ext_vector_type(8)));

#define WAITV(n) asm volatile("s_waitcnt vmcnt(" #n ")" ::: "memory")
#define LGKM0 do { asm volatile("s_waitcnt lgkmcnt(0)" ::: "memory"); \
                   __builtin_amdgcn_sched_barrier(0); } while (0)

template<int N> __device__ __forceinline__ void waitvT() {
  if constexpr (N == 0) WAITV(0);
  else if constexpr (N == 3) WAITV(3);
  else if constexpr (N == 4) WAITV(4);
  else if constexpr (N == 6) WAITV(6);
  else if constexpr (N == 8) WAITV(8);
}

__device__ __forceinline__ unsigned short f2bf(float f) {
  union { float f; unsigned u; } x; x.f = f;
  unsigned u = x.u;
  unsigned r = (u + 0x7FFFu + ((u >> 16) & 1u)) >> 16;
  return (unsigned short)r;
}

__device__ __forceinline__ void gld16(const void* g, void* l) {
  __builtin_amdgcn_global_load_lds(
      (const __attribute__((address_space(1))) unsigned int*)g,
      (__attribute__((address_space(3))) unsigned int*)l, 16, 0, 0);
}

// raw barrier (no compiler vmcnt(0) drain) + motion fence (rule #18)
__device__ __forceinline__ void barrier_sync() {
  asm volatile("" ::: "memory");
  __builtin_amdgcn_s_barrier();
  asm volatile("" ::: "memory");
  __builtin_amdgcn_sched_barrier(0);
}

// ---------------- gate ----------------------------------------------------
__global__ __launch_bounds__(256) void gate_kernel(
    const float* __restrict__ tb, const float* __restrict__ W,
    const float* __restrict__ bias, float* __restrict__ gate) {
  int t = threadIdx.x;
  int b = t >> 6, l = t & 63;
  float s = tb[b * TB_ + l] * W[l] + tb[b * TB_ + 64 + l] * W[64 + l];
  #pragma unroll
  for (int off = 32; off > 0; off >>= 1) s += __shfl_down(s, off, 64);
  if (l == 0) gate[b] = 1.0f / (1.0f + __expf(-(s + bias[0])));
}

// ---------------- f32 -> bf16 bulk convert --------------------------------
__global__ __launch_bounds__(256) void cvt_bf16_kernel(
    const float* __restrict__ src, short* __restrict__ dst) {
  size_t g = (size_t)blockIdx.x * 256 + threadIdx.x;
  v4f v = *(const v4f*)(src + g * 4);
  s16x4 o;
  o[0] = (short)f2bf(v[0]); o[1] = (short)f2bf(v[1]);
  o[2] = (short)f2bf(v[2]); o[3] = (short)f2bf(v[3]);
  *(s16x4*)(dst + g * 4) = o;
}

// ---------------- V [b][s][d] f32 -> V^T [b][d][s] bf16 -------------------
__global__ __launch_bounds__(256) void vT_kernel(
    const float* __restrict__ V, short* __restrict__ VT) {
  __shared__ float tile[64][65];
  int b = blockIdx.z;
  int s0 = blockIdx.x * 64, d0 = blockIdx.y * 64;
  int t = threadIdx.x;
  int tc = t & 63, tr4 = t >> 6;
  const float* src = V + ((size_t)b * S_ + s0) * D_ + d0;
  #pragma unroll
  for (int p = 0; p < 16; ++p) {
    int r = p * 4 + tr4;
    tile[r][tc] = src[(size_t)r * D_ + tc];
  }
  __syncthreads();
  short* dst = VT + ((size_t)b * D_ + d0) * S_ + s0;
  #pragma unroll
  for (int p = 0; p < 16; ++p) {
    int r = p * 4 + tr4;
    dst[(size_t)r * S_ + tc] = (short)f2bf(tile[tc][r]);
  }
}

// ---------------- deep-pipelined GEMM: C = A(MxK) . B(NxK)^T --------------
// BM=256, BK=32, 4 LDS buffers, prefetch depth 3 tiles, 2 phases/tile,
// counted vmcnt only at tile start (T4), XOR slot swizzle slot=hi^((r>>1)&3)
// via inverse-swizzled global source (T2, rule 21), setprio MFMA (T5).
// Race-free by construction: stage(t+3) writes buf (t-1)&3 whose reads
// finished before tile t's start barrier.
template<int MF, int WNC, int BLOADS, int KT, int BROWS, int LDC, bool GATED>
__global__ __launch_bounds__(512, 2) void gemm_pipe(
    const short* __restrict__ Ag, const short* __restrict__ Bg,
    const float* __restrict__ gate, float* __restrict__ Cg) {
  extern __shared__ char lds[];
  constexpr int NF = 4;                   // n-frags per wave
  constexpr int PH_MF = MF / 2;           // m-frags per phase
  constexpr int NT = KT / 32;             // K-tiles
  constexpr int ABYTES = 256 * 64;        // 16 KB (256 rows x 32 bf16)
  constexpr int BROWS_T = WNC * NF * 16;  // B-tile rows (= BN)
  constexpr int BBYTES = BROWS_T * 64;
  constexpr int BUFB = ABYTES + BBYTES;
  constexpr int LSTEADY = 2 * (2 + BLOADS);
  constexpr int LP1 = 2 + BLOADS;

  int wg = blockIdx.x;
  int swz = (wg & 7) * 32 + (wg >> 3);    // 256 wgs -> bijective XCD chunk
  int b = swz >> 6;
  int rem = swz & 63;
  int m0 = (rem >> 3) * 256;
  int n0 = (rem & 7) * BROWS_T;

  int tid = threadIdx.x;
  int w = tid >> 6, l = tid & 63;
  int wm = w / WNC, wn = w % WNC;

  const short* Ab = Ag + (size_t)b * S_ * KT + (size_t)m0 * KT;
  const short* Bb = Bg + (size_t)b * BROWS * KT + (size_t)n0 * KT;

  // staging: linear LDS dest (gld16 requirement); inverse-swizzled global col
  int tid4 = tid >> 2;
  int slog8 = ((tid & 3) ^ ((tid >> 3) & 3)) * 8;   // shorts
  // read side: per-lane swizzled 16B slot
  int fr = l & 15;
  int hi = l >> 4;
  int sl16 = (hi ^ ((l >> 1) & 3)) * 16;

  v4f acc[MF][NF];
  #pragma unroll
  for (int m = 0; m < MF; ++m)
    #pragma unroll
    for (int n = 0; n < NF; ++n)
      #pragma unroll
      for (int j = 0; j < 4; ++j) acc[m][n][j] = 0.0f;

  auto stageA = [&](int tt) {
    char* La = lds + (tt & 3) * BUFB;
    const short* src = Ab + (size_t)tid4 * KT + tt * 32 + slog8;
    gld16(src, La + tid * 16);
    gld16(src + (size_t)128 * KT, La + 8192 + tid * 16);
  };
  auto stageB = [&](int tt) {
    char* Lb = lds + (tt & 3) * BUFB + ABYTES;
    const short* src = Bb + (size_t)tid4 * KT + tt * 32 + slog8;
    gld16(src, Lb + tid * 16);
    if constexpr (BLOADS == 2)
      gld16(src + (size_t)128 * KT, Lb + 8192 + tid * 16);
  };

  stageA(0); stageB(0); stageA(1); stageB(1); stageA(2); stageB(2);

  s16x8 bf[NF];
  for (int t = 0; t < NT; ++t) {
    if (t < NT - 2) waitvT<LSTEADY>();
    else if (t == NT - 2) waitvT<LP1>();
    else waitvT<0>();
    barrier_sync();
    const char* base = lds + (t & 3) * BUFB;
    // ---- phase 0 ----
    {
      #pragma unroll
      for (int n = 0; n < NF; ++n)
        bf[n] = *(const s16x8*)(base + ABYTES +
                 (size_t)(wn * 64 + n * 16 + fr) * 64 + sl16);
      s16x8 af[PH_MF];
      #pragma unroll
      for (int i = 0; i < PH_MF; ++i)
        af[i] = *(const s16x8*)(base +
                 (size_t)(wm * MF * 16 + i * 16 + fr) * 64 + sl16);
      if (t + 3 < NT) stageA(t + 3);
      LGKM0;
      __builtin_amdgcn_s_setprio(1);
      #pragma unroll
      for (int i = 0; i < PH_MF; ++i)
        #pragma unroll
        for (int n = 0; n < NF; ++n)
          acc[i][n] = __builtin_amdgcn_mfma_f32_16x16x32_bf16(
              af[i], bf[n], acc[i][n], 0, 0, 0);
      __builtin_amdgcn_s_setprio(0);
    }
    barrier_sync();
    // ---- phase 1 ----
    {
      s16x8 af[PH_MF];
      #pragma unroll
      for (int i = 0; i < PH_MF; ++i)
        af[i] = *(const s16x8*)(base +
                 (size_t)(wm * MF * 16 + (PH_MF + i) * 16 + fr) * 64 + sl16);
      if (t + 3 < NT) stageB(t + 3);
      LGKM0;
      __builtin_amdgcn_s_setprio(1);
      #pragma unroll
      for (int i = 0; i < PH_MF; ++i)
        #pragma unroll
        for (int n = 0; n < NF; ++n)
          acc[PH_MF + i][n] = __builtin_amdgcn_mfma_f32_16x16x32_bf16(
              af[i], bf[n], acc[PH_MF + i][n], 0, 0, 0);
      __builtin_amdgcn_s_setprio(0);
    }
  }

  float g = 1.0f;
  if constexpr (GATED) g = gate[b] * 0.03125f;   // sigmoid-gate / sqrt(1024)
  float* Cb = Cg + (size_t)b * S_ * LDC +
              (size_t)(m0 + wm * MF * 16) * LDC + n0 + wn * 64;
  #pragma unroll
  for (int mf = 0; mf < MF; ++mf)
    #pragma unroll
    for (int n = 0; n < NF; ++n) {
      int r0 = mf * 16 + hi * 4;
      int c = n * 16 + fr;
      #pragma unroll
      for (int j = 0; j < 4; ++j)
        Cb[(size_t)(r0 + j) * LDC + c] = acc[mf][n][j] * g;
    }
}

// ---------------- row softmax: f32 in-place + bf16 copy for PV ------------
__global__ __launch_bounds__(256) void softmax_kernel(
    float* __restrict__ attn, short* __restrict__ attnb) {
  size_t row = blockIdx.x;
  float* p = attn + row * S_;
  int t = threadIdx.x;
  v4f v0 = *(const v4f*)(p + t * 8);
  v4f v1 = *(const v4f*)(p + t * 8 + 4);
  float m = fmaxf(fmaxf(fmaxf(v0[0], v0[1]), fmaxf(v0[2], v0[3])),
                  fmaxf(fmaxf(v1[0], v1[1]), fmaxf(v1[2], v1[3])));
  #pragma unroll
  for (int off = 32; off > 0; off >>= 1) m = fmaxf(m, __shfl_xor(m, off, 64));
  __shared__ float rm[4], rs[4];
  if ((t & 63) == 0) rm[t >> 6] = m;
  __syncthreads();
  m = fmaxf(fmaxf(rm[0], rm[1]), fmaxf(rm[2], rm[3]));
  float e[8]; float sum = 0.0f;
  #pragma unroll
  for (int j = 0; j < 4; ++j) { e[j] = __expf(v0[j] - m); sum += e[j]; }
  #pragma unroll
  for (int j = 0; j < 4; ++j) { e[4 + j] = __expf(v1[j] - m); sum += e[4 + j]; }
  #pragma unroll
  for (int off = 32; off > 0; off >>= 1) sum += __shfl_xor(sum, off, 64);
  if ((t & 63) == 0) rs[t >> 6] = sum;
  __syncthreads();
  sum = rs[0] + rs[1] + rs[2] + rs[3];
  float inv = 1.0f / sum;
  #pragma unroll
  for (int j = 0; j < 4; ++j) v0[j] = e[j] * inv;
  #pragma unroll
  for (int j = 0; j < 4; ++j) v1[j] = e[4 + j] * inv;
  *(v4f*)(p + t * 8) = v0;
  *(v4f*)(p + t * 8 + 4) = v1;
  s16x8 ob;
  ob[0] = (short)f2bf(v0[0]); ob[1] = (short)f2bf(v0[1]);
  ob[2] = (short)f2bf(v0[2]); ob[3] = (short)f2bf(v0[3]);
  ob[4] = (short)f2bf(v1[0]); ob[5] = (short)f2bf(v1[1]);
  ob[6] = (short)f2bf(v1[2]); ob[7] = (short)f2bf(v1[3]);
  *(s16x8*)(attnb + row * S_ + t * 8) = ob;
}

extern "C" void kernel_launch(void* const* d_in, const int* in_sizes, int n_in,
                              void* d_out, int out_size, void* d_ws, size_t ws_size,
                              hipStream_t stream) {
  (void)in_sizes; (void)n_in; (void)out_size; (void)ws_size;
  const float* Q  = (const float*)d_in[0];
  const float* K  = (const float*)d_in[1];
  const float* V  = (const float*)d_in[2];
  const float* tb = (const float*)d_in[3];
  const float* W  = (const float*)d_in[4];
  const float* bias = (const float*)d_in[5];

  float* out  = (float*)d_out;                       // [4,2048,1024]
  float* attn = out + (size_t)B_ * S_ * D_;          // [4,2048,2048]

  char* ws = (char*)d_ws;
  float* gate = (float*)ws;                          // 4 floats
  short* Qb = (short*)(ws + 256);                    // bf16 [4][2048][1024]
  short* Kb = Qb + (size_t)B_ * S_ * D_;             // bf16 [4][2048][1024]
  short* VT = Kb + (size_t)B_ * S_ * D_;             // bf16 [4][1024][2048]
  short* attnb = Qb;                                 // reuse Qb+Kb: bf16 P

  // QK: MF=8, waves 2x4, BN=256; A=Qb, B=Kb[2048][1024], C=attn, gated
  auto* qkf = gemm_pipe<8, 4, 2, 1024, 2048, 2048, true>;
  // PV: MF=4, waves 4x2, BN=128; A=attnb[2048][2048], B=VT[1024][2048]
  auto* pvf = gemm_pipe<4, 2, 1, 2048, 1024, 1024, false>;
  constexpr int QK_LDS = 4 * (16384 + 16384);        // 131072
  constexpr int PV_LDS = 4 * (16384 + 8192);         //  98304
  (void)hipFuncSetAttribute((const void*)qkf,
      hipFuncAttributeMaxDynamicSharedMemorySize, QK_LDS);
  (void)hipFuncSetAttribute((const void*)pvf,
      hipFuncAttributeMaxDynamicSharedMemorySize, PV_LDS);

  gate_kernel<<<1, 256, 0, stream>>>(tb, W, bias, gate);
  cvt_bf16_kernel<<<8192, 256, 0, stream>>>(Q, Qb);
  cvt_bf16_kernel<<<8192, 256, 0, stream>>>(K, Kb);
  vT_kernel<<<dim3(32, 16, 4), 256, 0, stream>>>(V, VT);
  qkf<<<256, 512, QK_LDS, stream>>>(Qb, Kb, gate, attn);
  softmax_kernel<<<8192, 256, 0, stream>>>(attn, attnb);
  pvf<<<256, 512, PV_LDS, stream>>>(attnb, VT, gate, out);
}

// Round 8
// 142.062 us; speedup vs baseline: 1.0124x; 1.0124x over previous
//
#include <hip/hip_runtime.h>
#include <hip/hip_bf16.h>
#include <stdint.h>
#include <stddef.h>

#define B_  4
#define S_  2048
#define D_  1024
#define TB_ 128

typedef float v4f  __attribute__((ext_vector_type(4)));
typedef short s16x4 __attribute__((ext_vector_type(4)));
typedef short s16x8 __attribute__((ext_vector_type(8)));

#define WAITV(n) asm volatile("s_waitcnt vmcnt(" #n ")" ::: "memory")

__device__ __forceinline__ unsigned short f2bf(float f) {
  union { float f; unsigned u; } x; x.f = f;
  unsigned u = x.u;
  unsigned r = (u + 0x7FFFu + ((u >> 16) & 1u)) >> 16;
  return (unsigned short)r;
}

__device__ __forceinline__ void gld16(const void* g, void* l) {
  __builtin_amdgcn_global_load_lds(
      (const __attribute__((address_space(1))) unsigned int*)g,
      (__attribute__((address_space(3))) unsigned int*)l, 16, 0, 0);
}

// raw barrier: mem-clobber fences (pin memory ops) around s_barrier, then
// a scheduling fence. No vmcnt(0) drain (unlike __syncthreads).
__device__ __forceinline__ void barrier_sync() {
  asm volatile("" ::: "memory");
  __builtin_amdgcn_s_barrier();
  asm volatile("" ::: "memory");
  __builtin_amdgcn_sched_barrier(0);
}

// ---------------- gate ----------------------------------------------------
__global__ __launch_bounds__(256) void gate_kernel(
    const float* __restrict__ tb, const float* __restrict__ W,
    const float* __restrict__ bias, float* __restrict__ gate) {
  int t = threadIdx.x;
  int b = t >> 6, l = t & 63;
  float s = tb[b * TB_ + l] * W[l] + tb[b * TB_ + 64 + l] * W[64 + l];
  #pragma unroll
  for (int off = 32; off > 0; off >>= 1) s += __shfl_down(s, off, 64);
  if (l == 0) gate[b] = 1.0f / (1.0f + __expf(-(s + bias[0])));
}

// ---------------- f32 -> bf16 bulk convert --------------------------------
__global__ __launch_bounds__(256) void cvt_bf16_kernel(
    const float* __restrict__ src, short* __restrict__ dst) {
  size_t g = (size_t)blockIdx.x * 256 + threadIdx.x;
  v4f v = *(const v4f*)(src + g * 4);
  s16x4 o;
  o[0] = (short)f2bf(v[0]); o[1] = (short)f2bf(v[1]);
  o[2] = (short)f2bf(v[2]); o[3] = (short)f2bf(v[3]);
  *(s16x4*)(dst + g * 4) = o;
}

// ---------------- V [b][s][d] f32 -> V^T [b][d][s] bf16 -------------------
__global__ __launch_bounds__(256) void vT_kernel(
    const float* __restrict__ V, short* __restrict__ VT) {
  __shared__ float tile[64][65];
  int b = blockIdx.z;
  int s0 = blockIdx.x * 64, d0 = blockIdx.y * 64;
  int t = threadIdx.x;
  int tc = t & 63, tr4 = t >> 6;
  const float* src = V + ((size_t)b * S_ + s0) * D_ + d0;
  #pragma unroll
  for (int p = 0; p < 16; ++p) {
    int r = p * 4 + tr4;
    tile[r][tc] = src[(size_t)r * D_ + tc];
  }
  __syncthreads();
  short* dst = VT + ((size_t)b * D_ + d0) * S_ + s0;
  #pragma unroll
  for (int p = 0; p < 16; ++p) {
    int r = p * 4 + tr4;
    dst[(size_t)r * S_ + tc] = (short)f2bf(tile[tc][r]);
  }
}

// ---------------- phased pipelined GEMM: C = A(MxK) . B(NxK)^T ------------
// R5's proven ledger (BK=64, 2 LDS buffers, stage-then-counted-vmcnt) plus
// m196's per-phase interleave: reads issued BEFORE each phase barrier (ds
// latency hides in the barrier wait), 16-MFMA setprio cluster after. No
// manual lgkmcnt: compiler emits fine-grained waits (m97/m141 lesson).
// Barriers/tile = 2 + PH. Swizzle as R5 (verified passing).
template<int MF, int WNC, int BLOADS, int KT, int BROWS, int LDC, bool GATED>
__global__ __launch_bounds__(512, 2) void gemm_pipe(
    const short* __restrict__ Ag, const short* __restrict__ Bg,
    const float* __restrict__ gate, float* __restrict__ Cg) {
  extern __shared__ char lds[];
  constexpr int NF = 4;                   // n-frags per wave
  constexpr int PH = MF / 2;              // phases per K-tile
  constexpr int NT = KT / 64;             // K-tiles
  constexpr int BN = WNC * 64;            // B-tile rows
  constexpr int ABYTES = 256 * 128;       // 32 KB per K-tile
  constexpr int BBYTES = BN * 128;
  constexpr int BUFB = ABYTES + BBYTES;

  int wg = blockIdx.x;
  int swz = (wg & 7) * 32 + (wg >> 3);    // 256 wgs -> bijective XCD chunk
  int b = swz >> 6;
  int rem = swz & 63;
  int m0 = (rem >> 3) * 256;
  int n0 = (rem & 7) * BN;

  int tid = threadIdx.x;
  int w = tid >> 6, l = tid & 63;
  int wm = w / WNC, wn = w % WNC;

  const short* Ab = Ag + (size_t)b * S_ * KT + (size_t)m0 * KT;
  const short* Bb = Bg + (size_t)b * BROWS * KT + (size_t)n0 * KT;

  // staging: linear LDS dest; inverse-swizzled global col chunk (rule #21)
  int srow8 = l >> 3;
  int schunk = ((l & 7) ^ srow8) * 8;     // shorts
  // read side: swizzled 16B slot per k-half; row%8 == l&7 for all frag rows
  int fr = l & 15;
  int hi = l >> 4;
  int sl0 = ((hi) ^ (l & 7)) * 16;
  int sl1 = ((4 + hi) ^ (l & 7)) * 16;

  v4f acc[MF][NF];
  #pragma unroll
  for (int m = 0; m < MF; ++m)
    #pragma unroll
    for (int n = 0; n < NF; ++n)
      #pragma unroll
      for (int j = 0; j < 4; ++j) acc[m][n][j] = 0.0f;

  auto stage = [&](int t, int buf) {
    char* La = lds + buf * BUFB;
    char* Lb = La + ABYTES;
    const short* As = Ab + (size_t)t * 64 + schunk;
    #pragma unroll
    for (int j = 0; j < 4; ++j) {
      int blk = w * 4 + j;
      gld16(As + (size_t)(blk * 8 + srow8) * KT, La + blk * 1024);
    }
    const short* Bs = Bb + (size_t)t * 64 + schunk;
    #pragma unroll
    for (int j = 0; j < BLOADS; ++j) {
      int blk = w * BLOADS + j;
      gld16(Bs + (size_t)(blk * 8 + srow8) * KT, Lb + blk * 1024);
    }
  };

  stage(0, 0);
  int cur = 0;
  for (int t = 0; t < NT; ++t) {
    if (t + 1 < NT) {
      stage(t + 1, cur ^ 1);              // prefetch stays in flight
      if constexpr (BLOADS == 4) WAITV(8); else WAITV(6);
    } else {
      WAITV(0);
    }
    barrier_sync();                       // publish tile t
    const char* base = lds + cur * BUFB;
    const char* Bbase = base + ABYTES;
    // R0: issue all B reads + phase-0 A reads (latency hides in barrier)
    s16x8 bfr[NF][2];
    #pragma unroll
    for (int n = 0; n < NF; ++n) {
      const char* rp = Bbase + (size_t)(wn * 64 + n * 16 + fr) * 128;
      bfr[n][0] = *(const s16x8*)(rp + sl0);
      bfr[n][1] = *(const s16x8*)(rp + sl1);
    }
    s16x8 afc[2][2];
    #pragma unroll
    for (int i = 0; i < 2; ++i) {
      const char* rp = base + (size_t)(wm * (MF * 16) + i * 16 + fr) * 128;
      afc[i][0] = *(const s16x8*)(rp + sl0);
      afc[i][1] = *(const s16x8*)(rp + sl1);
    }
    barrier_sync();
    #pragma unroll
    for (int p = 0; p < PH; ++p) {
      s16x8 afn[2][2];
      if (p + 1 < PH) {                   // issue next phase's A reads first
        #pragma unroll
        for (int i = 0; i < 2; ++i) {
          const char* rp = base +
              (size_t)(wm * (MF * 16) + (2 * (p + 1) + i) * 16 + fr) * 128;
          afn[i][0] = *(const s16x8*)(rp + sl0);
          afn[i][1] = *(const s16x8*)(rp + sl1);
        }
      }
      __builtin_amdgcn_s_setprio(1);
      #pragma unroll
      for (int kh = 0; kh < 2; ++kh)
        #pragma unroll
        for (int i = 0; i < 2; ++i)
          #pragma unroll
          for (int n = 0; n < NF; ++n)
            acc[2 * p + i][n] = __builtin_amdgcn_mfma_f32_16x16x32_bf16(
                afc[i][kh], bfr[n][kh], acc[2 * p + i][n], 0, 0, 0);
      __builtin_amdgcn_s_setprio(0);
      if (p + 1 < PH) {
        afc[0][0] = afn[0][0]; afc[0][1] = afn[0][1];
        afc[1][0] = afn[1][0]; afc[1][1] = afn[1][1];
      }
      barrier_sync();                     // phase end (last = tile end)
    }
    cur ^= 1;
  }

  float g = 1.0f;
  if constexpr (GATED) g = gate[b] * 0.03125f;   // sigmoid-gate / sqrt(1024)
  float* Cb = Cg + (size_t)b * S_ * LDC +
              (size_t)(m0 + wm * (MF * 16)) * LDC + n0 + wn * 64;
  #pragma unroll
  for (int mf = 0; mf < MF; ++mf)
    #pragma unroll
    for (int n = 0; n < NF; ++n) {
      int r0 = mf * 16 + hi * 4;
      int c = n * 16 + fr;
      #pragma unroll
      for (int j = 0; j < 4; ++j)
        Cb[(size_t)(r0 + j) * LDC + c] = acc[mf][n][j] * g;
    }
}

// ---------------- row softmax: f32 in-place + bf16 copy for PV ------------
__global__ __launch_bounds__(256) void softmax_kernel(
    float* __restrict__ attn, short* __restrict__ attnb) {
  size_t row = blockIdx.x;
  float* p = attn + row * S_;
  int t = threadIdx.x;
  v4f v0 = *(const v4f*)(p + t * 8);
  v4f v1 = *(const v4f*)(p + t * 8 + 4);
  float m = fmaxf(fmaxf(fmaxf(v0[0], v0[1]), fmaxf(v0[2], v0[3])),
                  fmaxf(fmaxf(v1[0], v1[1]), fmaxf(v1[2], v1[3])));
  #pragma unroll
  for (int off = 32; off > 0; off >>= 1) m = fmaxf(m, __shfl_xor(m, off, 64));
  __shared__ float rm[4], rs[4];
  if ((t & 63) == 0) rm[t >> 6] = m;
  __syncthreads();
  m = fmaxf(fmaxf(rm[0], rm[1]), fmaxf(rm[2], rm[3]));
  float e[8]; float sum = 0.0f;
  #pragma unroll
  for (int j = 0; j < 4; ++j) { e[j] = __expf(v0[j] - m); sum += e[j]; }
  #pragma unroll
  for (int j = 0; j < 4; ++j) { e[4 + j] = __expf(v1[j] - m); sum += e[4 + j]; }
  #pragma unroll
  for (int off = 32; off > 0; off >>= 1) sum += __shfl_xor(sum, off, 64);
  if ((t & 63) == 0) rs[t >> 6] = sum;
  __syncthreads();
  sum = rs[0] + rs[1] + rs[2] + rs[3];
  float inv = 1.0f / sum;
  #pragma unroll
  for (int j = 0; j < 4; ++j) v0[j] = e[j] * inv;
  #pragma unroll
  for (int j = 0; j < 4; ++j) v1[j] = e[4 + j] * inv;
  *(v4f*)(p + t * 8) = v0;
  *(v4f*)(p + t * 8 + 4) = v1;
  s16x8 ob;
  ob[0] = (short)f2bf(v0[0]); ob[1] = (short)f2bf(v0[1]);
  ob[2] = (short)f2bf(v0[2]); ob[3] = (short)f2bf(v0[3]);
  ob[4] = (short)f2bf(v1[0]); ob[5] = (short)f2bf(v1[1]);
  ob[6] = (short)f2bf(v1[2]); ob[7] = (short)f2bf(v1[3]);
  *(s16x8*)(attnb + row * S_ + t * 8) = ob;
}

extern "C" void kernel_launch(void* const* d_in, const int* in_sizes, int n_in,
                              void* d_out, int out_size, void* d_ws, size_t ws_size,
                              hipStream_t stream) {
  (void)in_sizes; (void)n_in; (void)out_size; (void)ws_size;
  const float* Q  = (const float*)d_in[0];
  const float* K  = (const float*)d_in[1];
  const float* V  = (const float*)d_in[2];
  const float* tb = (const float*)d_in[3];
  const float* W  = (const float*)d_in[4];
  const float* bias = (const float*)d_in[5];

  float* out  = (float*)d_out;                       // [4,2048,1024]
  float* attn = out + (size_t)B_ * S_ * D_;          // [4,2048,2048]

  char* ws = (char*)d_ws;
  float* gate = (float*)ws;                          // 4 floats
  short* Qb = (short*)(ws + 256);                    // bf16 [4][2048][1024]
  short* Kb = Qb + (size_t)B_ * S_ * D_;             // bf16 [4][2048][1024]
  short* VT = Kb + (size_t)B_ * S_ * D_;             // bf16 [4][1024][2048]
  short* attnb = Qb;                                 // reuse Qb+Kb: bf16 P

  // QK: MF=8 (2x4 waves, BN=256), KT=1024; gated. PV: MF=4 (4x2, BN=128), KT=2048.
  auto* qkf = gemm_pipe<8, 4, 4, 1024, 2048, 2048, true>;
  auto* pvf = gemm_pipe<4, 2, 2, 2048, 1024, 1024, false>;
  constexpr int QK_LDS = 2 * (256 + 256) * 64 * 2;   // 131072
  constexpr int PV_LDS = 2 * (256 + 128) * 64 * 2;   //  98304
  (void)hipFuncSetAttribute((const void*)qkf,
      hipFuncAttributeMaxDynamicSharedMemorySize, QK_LDS);
  (void)hipFuncSetAttribute((const void*)pvf,
      hipFuncAttributeMaxDynamicSharedMemorySize, PV_LDS);

  gate_kernel<<<1, 256, 0, stream>>>(tb, W, bias, gate);
  cvt_bf16_kernel<<<8192, 256, 0, stream>>>(Q, Qb);
  cvt_bf16_kernel<<<8192, 256, 0, stream>>>(K, Kb);
  vT_kernel<<<dim3(32, 16, 4), 256, 0, stream>>>(V, VT);
  qkf<<<256, 512, QK_LDS, stream>>>(Qb, Kb, gate, attn);
  softmax_kernel<<<8192, 256, 0, stream>>>(attn, attnb);
  pvf<<<256, 512, PV_LDS, stream>>>(attnb, VT, gate, out);
}

// Round 9
// 136.942 us; speedup vs baseline: 1.0503x; 1.0374x over previous
//
#include <hip/hip_runtime.h>
#include <hip/hip_bf16.h>
#include <stdint.h>
#include <stddef.h>

#define B_  4
#define S_  2048
#define D_  1024
#define TB_ 128

typedef float v4f  __attribute__((ext_vector_type(4)));
typedef float v16f __attribute__((ext_vector_type(16)));
typedef short s16x4 __attribute__((ext_vector_type(4)));
typedef short s16x8 __attribute__((ext_vector_type(8)));

#define WAITV(n) asm volatile("s_waitcnt vmcnt(" #n ")" ::: "memory")

__device__ __forceinline__ unsigned short f2bf(float f) {
  union { float f; unsigned u; } x; x.f = f;
  unsigned u = x.u;
  unsigned r = (u + 0x7FFFu + ((u >> 16) & 1u)) >> 16;
  return (unsigned short)r;
}

__device__ __forceinline__ void gld16(const void* g, void* l) {
  __builtin_amdgcn_global_load_lds(
      (const __attribute__((address_space(1))) unsigned int*)g,
      (__attribute__((address_space(3))) unsigned int*)l, 16, 0, 0);
}

// raw barrier (no vmcnt(0) drain) + motion fence
__device__ __forceinline__ void barrier_sync() {
  asm volatile("" ::: "memory");
  __builtin_amdgcn_s_barrier();
  asm volatile("" ::: "memory");
  __builtin_amdgcn_sched_barrier(0);
}

// ---------------- prep: gate + cvt(Q) + cvt(K) + V^T, one dispatch --------
__global__ __launch_bounds__(256) void prep_kernel(
    const float* __restrict__ Q, const float* __restrict__ K,
    const float* __restrict__ V, const float* __restrict__ tb,
    const float* __restrict__ W, const float* __restrict__ bias,
    short* __restrict__ Qb, short* __restrict__ Kb,
    short* __restrict__ VT, float* __restrict__ gate) {
  __shared__ float tile[64][65];
  int bid = blockIdx.x;
  int t = threadIdx.x;
  if (bid < 16384) {                       // bulk f32->bf16 convert (Q or K)
    const float* src = bid < 8192 ? Q : K;
    short* dst = bid < 8192 ? Qb : Kb;
    size_t g = (size_t)(bid & 8191) * 256 + t;
    v4f v = *(const v4f*)(src + g * 4);
    s16x4 o;
    o[0] = (short)f2bf(v[0]); o[1] = (short)f2bf(v[1]);
    o[2] = (short)f2bf(v[2]); o[3] = (short)f2bf(v[3]);
    *(s16x4*)(dst + g * 4) = o;
  } else if (bid < 18432) {                // V [b][s][d] -> V^T [b][d][s]
    int v = bid - 16384;
    int b = v >> 9;
    int rem = v & 511;
    int s0 = (rem & 31) * 64, d0 = (rem >> 5) * 64;
    int tc = t & 63, tr4 = t >> 6;
    const float* src = V + ((size_t)b * S_ + s0) * D_ + d0;
    #pragma unroll
    for (int p = 0; p < 16; ++p) {
      int r = p * 4 + tr4;
      tile[r][tc] = src[(size_t)r * D_ + tc];
    }
    __syncthreads();
    short* dst = VT + ((size_t)b * D_ + d0) * S_ + s0;
    #pragma unroll
    for (int p = 0; p < 16; ++p) {
      int r = p * 4 + tr4;
      dst[(size_t)r * S_ + tc] = (short)f2bf(tile[tc][r]);
    }
  } else {                                 // gate: sigmoid(tb @ W + b)
    int b = t >> 6, l = t & 63;
    float s = tb[b * TB_ + l] * W[l] + tb[b * TB_ + 64 + l] * W[64 + l];
    #pragma unroll
    for (int off = 32; off > 0; off >>= 1) s += __shfl_down(s, off, 64);
    if (l == 0) gate[b] = 1.0f / (1.0f + __expf(-(s + bias[0])));
  }
}

// ---------------- pipelined GEMM (32x32x16 MFMA): C = A . B^T -------------
// R5's proven skeleton (BK=64, 2 LDS buffers, counted vmcnt, XOR slot
// swizzle, setprio) with the MFMA shape swapped to 32x32x16 (2382 vs 2075
// TF ceiling, half the instruction count). Staging/swizzle byte-identical
// to R5. A/B frag: row=lane&31, k=8*(lane>>5)+e. C/D (m74/m101): col=
// lane&31, row=(reg&3)+8*(reg>>2)+4*(lane>>5).
template<int MFR, int NFR, int WNC, int BLOADS, int KT, int BROWS, int LDC,
         bool GATED>
__global__ __launch_bounds__(512, 2) void gemm_pipe(
    const short* __restrict__ Ag, const short* __restrict__ Bg,
    const float* __restrict__ gate, float* __restrict__ Cg) {
  extern __shared__ char lds[];
  constexpr int NT = KT / 64;             // K-tiles
  constexpr int BN = WNC * NFR * 32;      // B-tile rows
  constexpr int ABYTES = 256 * 128;       // 32 KB per K-tile
  constexpr int BBYTES = BN * 128;
  constexpr int BUFB = ABYTES + BBYTES;

  int wg = blockIdx.x;
  int swz = (wg & 7) * 32 + (wg >> 3);    // 256 wgs -> bijective XCD chunk
  int b = swz >> 6;
  int rem = swz & 63;
  int m0 = (rem >> 3) * 256;
  int n0 = (rem & 7) * BN;

  int tid = threadIdx.x;
  int w = tid >> 6, l = tid & 63;
  int wm = w / WNC, wn = w % WNC;
  int l7 = l & 7, col31 = l & 31, hi2 = l >> 5;

  const short* Ab = Ag + (size_t)b * S_ * KT + (size_t)m0 * KT;
  const short* Bb = Bg + (size_t)b * BROWS * KT + (size_t)n0 * KT;

  // staging: linear LDS dest; inverse-swizzled global chunk (rule #21)
  int srow8 = l >> 3;
  int schunk = ((l & 7) ^ srow8) * 8;     // shorts

  v16f acc[MFR][NFR];
  #pragma unroll
  for (int m = 0; m < MFR; ++m)
    #pragma unroll
    for (int n = 0; n < NFR; ++n)
      #pragma unroll
      for (int j = 0; j < 16; ++j) acc[m][n][j] = 0.0f;

  auto stage = [&](int t, int buf) {
    char* La = lds + buf * BUFB;
    char* Lb = La + ABYTES;
    const short* As = Ab + (size_t)t * 64 + schunk;
    #pragma unroll
    for (int j = 0; j < 4; ++j) {
      int blk = w * 4 + j;
      gld16(As + (size_t)(blk * 8 + srow8) * KT, La + blk * 1024);
    }
    const short* Bs = Bb + (size_t)t * 64 + schunk;
    #pragma unroll
    for (int j = 0; j < BLOADS; ++j) {
      int blk = w * BLOADS + j;
      gld16(Bs + (size_t)(blk * 8 + srow8) * KT, Lb + blk * 1024);
    }
  };

  stage(0, 0);
  int cur = 0;
  for (int t = 0; t < NT; ++t) {
    if (t + 1 < NT) {
      stage(t + 1, cur ^ 1);              // prefetch stays in flight
      if constexpr (BLOADS == 4) WAITV(8); else WAITV(6);
    } else {
      WAITV(0);
    }
    barrier_sync();                       // publish tile t
    const char* Abase = lds + cur * BUFB;
    const char* Bbase = Abase + ABYTES;
    #pragma unroll
    for (int ks = 0; ks < 4; ++ks) {
      int slot = ((ks * 2 + hi2) ^ l7) * 16;
      s16x8 bfr[NFR], af[MFR];
      #pragma unroll
      for (int n = 0; n < NFR; ++n)
        bfr[n] = *(const s16x8*)(Bbase +
                 (size_t)(wn * (NFR * 32) + n * 32 + col31) * 128 + slot);
      #pragma unroll
      for (int m = 0; m < MFR; ++m)
        af[m] = *(const s16x8*)(Abase +
                 (size_t)(wm * (MFR * 32) + m * 32 + col31) * 128 + slot);
      __builtin_amdgcn_s_setprio(1);
      #pragma unroll
      for (int m = 0; m < MFR; ++m)
        #pragma unroll
        for (int n = 0; n < NFR; ++n)
          acc[m][n] = __builtin_amdgcn_mfma_f32_32x32x16_bf16(
              af[m], bfr[n], acc[m][n], 0, 0, 0);
      __builtin_amdgcn_s_setprio(0);
    }
    barrier_sync();                       // reads of buf[cur] done
    cur ^= 1;
  }

  float g = 1.0f;
  if constexpr (GATED) g = gate[b] * 0.03125f;   // sigmoid-gate / sqrt(1024)
  float* Cb = Cg + (size_t)b * S_ * LDC +
              (size_t)(m0 + wm * (MFR * 32)) * LDC + n0 + wn * (NFR * 32);
  #pragma unroll
  for (int mf = 0; mf < MFR; ++mf)
    #pragma unroll
    for (int nf = 0; nf < NFR; ++nf) {
      int c = nf * 32 + col31;
      #pragma unroll
      for (int q = 0; q < 4; ++q)
        #pragma unroll
        for (int j = 0; j < 4; ++j) {
          int r = mf * 32 + q * 8 + 4 * hi2 + j;
          Cb[(size_t)r * LDC + c] = acc[mf][nf][q * 4 + j] * g;
        }
    }
}

// ---------------- row softmax: f32 in-place + bf16 copy for PV ------------
__global__ __launch_bounds__(256) void softmax_kernel(
    float* __restrict__ attn, short* __restrict__ attnb) {
  size_t row = blockIdx.x;
  float* p = attn + row * S_;
  int t = threadIdx.x;
  v4f v0 = *(const v4f*)(p + t * 8);
  v4f v1 = *(const v4f*)(p + t * 8 + 4);
  float m = fmaxf(fmaxf(fmaxf(v0[0], v0[1]), fmaxf(v0[2], v0[3])),
                  fmaxf(fmaxf(v1[0], v1[1]), fmaxf(v1[2], v1[3])));
  #pragma unroll
  for (int off = 32; off > 0; off >>= 1) m = fmaxf(m, __shfl_xor(m, off, 64));
  __shared__ float rm[4], rs[4];
  if ((t & 63) == 0) rm[t >> 6] = m;
  __syncthreads();
  m = fmaxf(fmaxf(rm[0], rm[1]), fmaxf(rm[2], rm[3]));
  float e[8]; float sum = 0.0f;
  #pragma unroll
  for (int j = 0; j < 4; ++j) { e[j] = __expf(v0[j] - m); sum += e[j]; }
  #pragma unroll
  for (int j = 0; j < 4; ++j) { e[4 + j] = __expf(v1[j] - m); sum += e[4 + j]; }
  #pragma unroll
  for (int off = 32; off > 0; off >>= 1) sum += __shfl_xor(sum, off, 64);
  if ((t & 63) == 0) rs[t >> 6] = sum;
  __syncthreads();
  sum = rs[0] + rs[1] + rs[2] + rs[3];
  float inv = 1.0f / sum;
  #pragma unroll
  for (int j = 0; j < 4; ++j) v0[j] = e[j] * inv;
  #pragma unroll
  for (int j = 0; j < 4; ++j) v1[j] = e[4 + j] * inv;
  *(v4f*)(p + t * 8) = v0;
  *(v4f*)(p + t * 8 + 4) = v1;
  s16x8 ob;
  ob[0] = (short)f2bf(v0[0]); ob[1] = (short)f2bf(v0[1]);
  ob[2] = (short)f2bf(v0[2]); ob[3] = (short)f2bf(v0[3]);
  ob[4] = (short)f2bf(v1[0]); ob[5] = (short)f2bf(v1[1]);
  ob[6] = (short)f2bf(v1[2]); ob[7] = (short)f2bf(v1[3]);
  *(s16x8*)(attnb + row * S_ + t * 8) = ob;
}

extern "C" void kernel_launch(void* const* d_in, const int* in_sizes, int n_in,
                              void* d_out, int out_size, void* d_ws, size_t ws_size,
                              hipStream_t stream) {
  (void)in_sizes; (void)n_in; (void)out_size; (void)ws_size;
  const float* Q  = (const float*)d_in[0];
  const float* K  = (const float*)d_in[1];
  const float* V  = (const float*)d_in[2];
  const float* tb = (const float*)d_in[3];
  const float* W  = (const float*)d_in[4];
  const float* bias = (const float*)d_in[5];

  float* out  = (float*)d_out;                       // [4,2048,1024]
  float* attn = out + (size_t)B_ * S_ * D_;          // [4,2048,2048]

  char* ws = (char*)d_ws;
  float* gate = (float*)ws;                          // 4 floats
  short* Qb = (short*)(ws + 256);                    // bf16 [4][2048][1024]
  short* Kb = Qb + (size_t)B_ * S_ * D_;             // bf16 [4][2048][1024]
  short* VT = Kb + (size_t)B_ * S_ * D_;             // bf16 [4][1024][2048]
  short* attnb = Qb;                                 // reuse Qb+Kb: bf16 P

  // QK: wave 128x64 (MFR=4,NFR=2), 2x4 waves, BN=256, KT=1024, gated.
  auto* qkf = gemm_pipe<4, 2, 4, 4, 1024, 2048, 2048, true>;
  // PV: wave 64x64 (MFR=2,NFR=2), 4x2 waves, BN=128, KT=2048.
  auto* pvf = gemm_pipe<2, 2, 2, 2, 2048, 1024, 1024, false>;
  constexpr int QK_LDS = 2 * (256 + 256) * 64 * 2;   // 131072
  constexpr int PV_LDS = 2 * (256 + 128) * 64 * 2;   //  98304
  (void)hipFuncSetAttribute((const void*)qkf,
      hipFuncAttributeMaxDynamicSharedMemorySize, QK_LDS);
  (void)hipFuncSetAttribute((const void*)pvf,
      hipFuncAttributeMaxDynamicSharedMemorySize, PV_LDS);

  prep_kernel<<<18433, 256, 0, stream>>>(Q, K, V, tb, W, bias,
                                         Qb, Kb, VT, gate);
  qkf<<<256, 512, QK_LDS, stream>>>(Qb, Kb, gate, attn);
  softmax_kernel<<<8192, 256, 0, stream>>>(attn, attnb);
  pvf<<<256, 512, PV_LDS, stream>>>(attnb, VT, gate, out);
}